// Round 19
// baseline (330.939 us; speedup 1.0000x reference)
//
#include <hip/hip_runtime.h>
#include <hip/hip_bf16.h>
#include <stdint.h>

#define NEXP 8
#define HD 1024
#define ID 3584
#define NTOK 2048
#define NSLOT 4096          // NTOK * TOPK
#define SLOT_PAD 256
#define NSLOT_ALLOC (NSLOT + SLOT_PAD)
#define WN (NEXP * ID * HD)   // elements per weight tensor = 29,360,128

typedef unsigned short u16;
typedef __attribute__((ext_vector_type(8))) short s16x8;
typedef __attribute__((ext_vector_type(4))) short s16x4;
typedef __attribute__((ext_vector_type(4))) float f32x4;

__device__ __forceinline__ u16 f2bf(float f) {
    __hip_bfloat16 h = __float2bfloat16(f);   // RNE
    union { __hip_bfloat16 h; u16 u; } v; v.h = h; return v.u;
}

__device__ __forceinline__ s16x8 cvt8(f32x4 a, f32x4 b) {
    s16x8 o;
    o[0]=(short)f2bf(a[0]); o[1]=(short)f2bf(a[1]); o[2]=(short)f2bf(a[2]); o[3]=(short)f2bf(a[3]);
    o[4]=(short)f2bf(b[0]); o[5]=(short)f2bf(b[1]); o[6]=(short)f2bf(b[2]); o[7]=(short)f2bf(b[3]);
    return o;
}

__device__ __forceinline__ void glds16(const void* g, void* l) {
    __builtin_amdgcn_global_load_lds((const __attribute__((address_space(1))) unsigned*)g,
                                     (__attribute__((address_space(3))) unsigned*)l, 16, 0, 0);
}

// wave-coalesced fp32->bf16: per block 2048 f32x4 (32 KB in / 16 KB out).
// Each load instruction: lane-stride 16 B (consecutive lanes -> consecutive chunks).
// Each store: s16x4 = 8 B/lane, consecutive. 8 independent loads in flight/thread.
__device__ __forceinline__ void cvt_blk(const float* __restrict__ src, u16* __restrict__ dst, int blk) {
    size_t base = (size_t)blk * 2048 + threadIdx.x;
    const f32x4* s = (const f32x4*)src;
    s16x4* d = (s16x4*)dst;
#pragma unroll
    for (int j = 0; j < 8; ++j) {
        f32x4 v = s[base + j * 256];
        s16x4 o;
        o[0] = (short)f2bf(v[0]); o[1] = (short)f2bf(v[1]);
        o[2] = (short)f2bf(v[2]); o[3] = (short)f2bf(v[3]);
        d[base + j * 256] = o;
    }
}

// ---------------- K0: zero counters ----------------
__global__ void init_kernel(int* __restrict__ counts) {
    if (threadIdx.x < 16) counts[threadIdx.x] = 0;   // counts[8] + counts2[8]
}

// ---------------- K1: FAT preprocessing ----------------
// blocks [0,512): router, 4 tokens/block.
// blocks [512,4096): w1 cvt   (3584 blocks x 2048 f32x4 = 29,360,128 elems = WN exactly)
// blocks [4096,7680): w3 cvt
// blocks [7680,7936): x cvt   (256 blocks x 2048 f32x4 = 2,097,152 = NTOK*HD exactly)
#define RT_BLOCKS 512
#define WCV_BLOCKS 3584
#define XCV_BLOCKS 256
#define PRE_BLOCKS (RT_BLOCKS + 2 * WCV_BLOCKS + XCV_BLOCKS)   // 7936
__global__ __launch_bounds__(256)
void pre_kernel(const float* __restrict__ x, const float* __restrict__ wg,
                int* __restrict__ topk_idx, float* __restrict__ topk_w,
                int* __restrict__ counts,
                u16* __restrict__ xbf,
                const float* __restrict__ w1, u16* __restrict__ w1bf,
                const float* __restrict__ w3, u16* __restrict__ w3bf) {
    int bid = blockIdx.x;
    if (bid >= RT_BLOCKS) {
        if (bid < RT_BLOCKS + WCV_BLOCKS) {
            cvt_blk(w1, w1bf, bid - RT_BLOCKS);
        } else if (bid < RT_BLOCKS + 2 * WCV_BLOCKS) {
            cvt_blk(w3, w3bf, bid - RT_BLOCKS - WCV_BLOCKS);
        } else {
            cvt_blk(x, xbf, bid - RT_BLOCKS - 2 * WCV_BLOCKS);
        }
        return;
    }
    // ---- router: 4 waves/block, 1 token/wave, fp32 exact top-2 ----
    int t = bid * 4 + (threadIdx.x >> 6);
    int lane = threadIdx.x & 63;
    const float* xr = x + (size_t)t * HD;
    float acc[NEXP];
#pragma unroll
    for (int e = 0; e < NEXP; ++e) acc[e] = 0.f;
#pragma unroll
    for (int i = 0; i < HD / 256; ++i) {
        int h = i * 256 + lane * 4;
        f32x4 xv = *(const f32x4*)(xr + h);
#pragma unroll
        for (int e = 0; e < NEXP; ++e) {
            f32x4 wv = *(const f32x4*)(wg + e * HD + h);
            acc[e] += xv[0]*wv[0] + xv[1]*wv[1] + xv[2]*wv[2] + xv[3]*wv[3];
        }
    }
#pragma unroll
    for (int e = 0; e < NEXP; ++e) {
#pragma unroll
        for (int s = 32; s > 0; s >>= 1) acc[e] += __shfl_xor(acc[e], s, 64);
    }
    if (lane == 0) {
        int b0 = 0; float l0 = acc[0];
#pragma unroll
        for (int e = 1; e < NEXP; ++e) if (acc[e] > l0) { l0 = acc[e]; b0 = e; }
        int b1 = (b0 == 0) ? 1 : 0; float l1 = acc[b1];
#pragma unroll
        for (int e = 0; e < NEXP; ++e) {
            if (e == b0 || e == b1) continue;
            if (acc[e] > l1) { l1 = acc[e]; b1 = e; }
        }
        float w0 = 1.f / (1.f + expf(l1 - l0));   // renormalized top-2 softmax
        float w1v = 1.f - w0;
        topk_idx[2 * t] = b0; topk_idx[2 * t + 1] = b1;
        topk_w[2 * t] = w0;  topk_w[2 * t + 1] = w1v;
        atomicAdd(&counts[b0], 1);
        atomicAdd(&counts[b1], 1);
    }
}

// ---------------- K2: exclusive scan + pad rows ----------------
__global__ void scan_kernel(const int* __restrict__ counts, int* __restrict__ offsets,
                            int* __restrict__ rows) {
    if (threadIdx.x == 0) {
        int off = 0;
#pragma unroll
        for (int e = 0; e < NEXP; ++e) { offsets[e] = off; off += counts[e]; }
    }
    if (threadIdx.x < SLOT_PAD) rows[NSLOT + threadIdx.x] = 0;
}

// ---------------- K3: slot assignment ----------------
__global__ void assign_kernel(const int* __restrict__ topk_idx, const int* __restrict__ offsets,
                              int* __restrict__ counts2, int* __restrict__ rows,
                              int* __restrict__ slot_of) {
    int i = blockIdx.x * 256 + threadIdx.x;   // 0..4095
    int e = topk_idx[i];
    int pos = atomicAdd(&counts2[e], 1);
    int slot = offsets[e] + pos;
    rows[slot] = i >> 1;       // token id
    slot_of[i] = slot;
}

// ---------------- K5: FAT kernel: GEMM1 (g,u)+SwiGLU -> h  ||  w2 cvt ----------------
// R14/R15 structure (byte-identical): 2-barrier BK=64, 128x128 tile, 4 waves, 48 KB LDS,
// 8-granule XOR swizzle (verified conflict-free), T1 panel-XCD remap, fat w2-cvt.
#define G1_BLOCKS (NEXP * (NTOK / 128) * (ID / 128))   // 3584
#define CVT2_BLOCKS 1024
__global__ __launch_bounds__(256, 2)
void gemm1_kernel(const u16* __restrict__ xbf, const u16* __restrict__ w1bf,
                  const u16* __restrict__ w3bf, const int* __restrict__ counts,
                  const int* __restrict__ offsets, const int* __restrict__ rows,
                  u16* __restrict__ hbuf,
                  const float* __restrict__ w2, u16* __restrict__ w2bf) {
    __shared__ u16 As[128][64];    // 16 KB
    __shared__ u16 B1s[128][64];   // 16 KB
    __shared__ u16 B3s[128][64];   // 16 KB

    if (blockIdx.x >= G1_BLOCKS) {
        // w2 cvt side job: same coalesced mapping (1024 blocks, grid-stride by 2048 f32x4)
        const int nblk = WN / 4 / 2048;   // 3584 logical blocks
        for (int blk = blockIdx.x - G1_BLOCKS; blk < nblk; blk += CVT2_BLOCKS)
            cvt_blk(w2, w2bf, blk);
        return;
    }

    int bid = blockIdx.x;
    int gq = bid >> 7;            // 0..27
    int rm = bid & 127;
    int mt = rm >> 3;             // 0..15
    int g  = gq * 8 + (rm & 7);   // 0..223
    int e  = g / 28;              // NT = ID/128 = 28
    int nt = g - e * 28;

    int n_e = counts[e];
    int m0 = mt * 128;
    if (m0 >= n_e) return;
    int off = offsets[e];
    int n0 = nt * 128;

    int tid = threadIdx.x;
    int lane = tid & 63;
    int wid = tid >> 6;           // 0..3

    int rsub = lane >> 3;                       // 0..7
    int chunk = ((lane & 7) ^ rsub) * 8;        // pre-swizzled source offset (elems)
    int srow = wid * 32 + rsub;

    const u16 *srcA[4], *srcB1[4], *srcB3[4];
#pragma unroll
    for (int j = 0; j < 4; ++j) {
        int rl = srow + 8 * j;
        int tok = rows[off + m0 + rl];
        srcA[j]  = xbf  + (size_t)tok * HD + chunk;
        srcB1[j] = w1bf + ((size_t)e * ID + n0 + rl) * HD + chunk;
        srcB3[j] = w3bf + ((size_t)e * ID + n0 + rl) * HD + chunk;
    }

    f32x4 accg[4][4] = {}, accu[4][4] = {};
    int wm = (wid >> 1) * 64, wn = (wid & 1) * 64;
    int lr = lane & 15;
    int kk = lane >> 4;
    int ks0 = ((kk)     ^ (lr & 7)) * 8;
    int ks1 = ((4 + kk) ^ (lr & 7)) * 8;

    for (int k0 = 0; k0 < HD; k0 += 64) {        // 16 steps
#pragma unroll
        for (int j = 0; j < 4; ++j) {
            glds16(srcA[j]  + k0, &As[wid * 32 + 8 * j][0]);
            glds16(srcB1[j] + k0, &B1s[wid * 32 + 8 * j][0]);
            glds16(srcB3[j] + k0, &B3s[wid * 32 + 8 * j][0]);
        }
        __syncthreads();
        s16x8 a[4], b1[4], b3[4];
#pragma unroll
        for (int f = 0; f < 4; ++f) {
            a[f]  = *(const s16x8*)&As[wm + f * 16 + lr][ks0];
            b1[f] = *(const s16x8*)&B1s[wn + f * 16 + lr][ks0];
            b3[f] = *(const s16x8*)&B3s[wn + f * 16 + lr][ks0];
        }
#pragma unroll
        for (int fm = 0; fm < 4; ++fm)
#pragma unroll
            for (int fn = 0; fn < 4; ++fn) {
                accg[fm][fn] = __builtin_amdgcn_mfma_f32_16x16x32_bf16(a[fm], b1[fn], accg[fm][fn], 0, 0, 0);
                accu[fm][fn] = __builtin_amdgcn_mfma_f32_16x16x32_bf16(a[fm], b3[fn], accu[fm][fn], 0, 0, 0);
            }
#pragma unroll
        for (int f = 0; f < 4; ++f) {
            a[f]  = *(const s16x8*)&As[wm + f * 16 + lr][ks1];
            b1[f] = *(const s16x8*)&B1s[wn + f * 16 + lr][ks1];
            b3[f] = *(const s16x8*)&B3s[wn + f * 16 + lr][ks1];
        }
#pragma unroll
        for (int fm = 0; fm < 4; ++fm)
#pragma unroll
            for (int fn = 0; fn < 4; ++fn) {
                accg[fm][fn] = __builtin_amdgcn_mfma_f32_16x16x32_bf16(a[fm], b1[fn], accg[fm][fn], 0, 0, 0);
                accu[fm][fn] = __builtin_amdgcn_mfma_f32_16x16x32_bf16(a[fm], b3[fn], accu[fm][fn], 0, 0, 0);
            }
        __syncthreads();
    }

    int lc = lane & 15;
    int lr4 = (lane >> 4) * 4;
#pragma unroll
    for (int fm = 0; fm < 4; ++fm) {
#pragma unroll
        for (int r = 0; r < 4; ++r) {
            int row = wm + fm * 16 + lr4 + r;
            if (m0 + row < n_e) {
                size_t base = (size_t)(off + m0 + row) * ID + n0 + wn;
#pragma unroll
                for (int fn = 0; fn < 4; ++fn) {
                    float g2 = accg[fm][fn][r];
                    float u = accu[fm][fn][r];
                    float hv = g2 * u / (1.f + expf(-g2));   // silu(g)*u
                    hbuf[base + fn * 16 + lc] = f2bf(hv);
                }
            }
        }
    }
}

// ---------------- K6: GEMM2 h @ w2bf^T -> per-slot fp32, KSPLIT=1, BK=64 ----------------
__global__ __launch_bounds__(256, 2)
void gemm2_kernel(const u16* __restrict__ hbuf, const u16* __restrict__ w2bf,
                  const int* __restrict__ counts, const int* __restrict__ offsets,
                  float* __restrict__ out2) {
    int bid = blockIdx.x;
    int e = bid & 7;
    int inner = bid >> 3;        // 0..127
    int mt = inner >> 3;         // 0..15
    int nt = inner & 7;          // 0..7

    int n_e = counts[e];
    int m0 = mt * 128;
    if (m0 >= n_e) return;
    int off = offsets[e];
    int n0 = nt * 128;

    __shared__ u16 As[128][64];   // 16 KB
    __shared__ u16 Bs[128][64];   // 16 KB

    int tid = threadIdx.x;
    int lane = tid & 63;
    int wid = tid >> 6;

    int rsub = lane >> 3;
    int chunk = ((lane & 7) ^ rsub) * 8;
    int srow = wid * 32 + rsub;

    const u16 *srcA[4], *srcB[4];
#pragma unroll
    for (int j = 0; j < 4; ++j) {
        int rl = srow + 8 * j;
        srcA[j] = hbuf + (size_t)(off + m0 + rl) * ID + chunk;
        srcB[j] = w2bf + ((size_t)e * HD + n0 + rl) * ID + chunk;
    }

    f32x4 acc[4][4] = {};
    int wm = (wid >> 1) * 64, wn = (wid & 1) * 64;
    int lr = lane & 15;
    int kk = lane >> 4;
    int ks0 = ((kk)     ^ (lr & 7)) * 8;
    int ks1 = ((4 + kk) ^ (lr & 7)) * 8;

    for (int k0 = 0; k0 < ID; k0 += 64) {        // 56 steps
#pragma unroll
        for (int j = 0; j < 4; ++j) {
            glds16(srcA[j] + k0, &As[wid * 32 + 8 * j][0]);
            glds16(srcB[j] + k0, &Bs[wid * 32 + 8 * j][0]);
        }
        __syncthreads();
        s16x8 a[4], b[4];
#pragma unroll
        for (int f = 0; f < 4; ++f) {
            a[f] = *(const s16x8*)&As[wm + f * 16 + lr][ks0];
            b[f] = *(const s16x8*)&Bs[wn + f * 16 + lr][ks0];
        }
#pragma unroll
        for (int fm = 0; fm < 4; ++fm)
#pragma unroll
            for (int fn = 0; fn < 4; ++fn)
                acc[fm][fn] = __builtin_amdgcn_mfma_f32_16x16x32_bf16(a[fm], b[fn], acc[fm][fn], 0, 0, 0);
#pragma unroll
        for (int f = 0; f < 4; ++f) {
            a[f] = *(const s16x8*)&As[wm + f * 16 + lr][ks1];
            b[f] = *(const s16x8*)&Bs[wn + f * 16 + lr][ks1];
        }
#pragma unroll
        for (int fm = 0; fm < 4; ++fm)
#pragma unroll
            for (int fn = 0; fn < 4; ++fn)
                acc[fm][fn] = __builtin_amdgcn_mfma_f32_16x16x32_bf16(a[fm], b[fn], acc[fm][fn], 0, 0, 0);
        __syncthreads();
    }

    int lc = lane & 15;
    int lr4 = (lane >> 4) * 4;
#pragma unroll
    for (int fm = 0; fm < 4; ++fm) {
#pragma unroll
        for (int r = 0; r < 4; ++r) {
            int row = wm + fm * 16 + lr4 + r;
            if (m0 + row < n_e) {
                float* dst = out2 + (size_t)(off + m0 + row) * HD + n0 + wn;
#pragma unroll
                for (int fn = 0; fn < 4; ++fn)
                    dst[fn * 16 + lc] = acc[fm][fn][r];
            }
        }
    }
}

// ---------------- K7: weighted combine (single partial) ----------------
__global__ void combine_kernel(const float* __restrict__ out2, const int* __restrict__ slot_of,
                               const float* __restrict__ topk_w, float* __restrict__ y) {
    int i = blockIdx.x * 256 + threadIdx.x;   // over NTOK*HD/4
    int t = i >> 8;           // HD/4 = 256 float4 per token
    int c = i & 255;
    int s0 = slot_of[2 * t], s1 = slot_of[2 * t + 1];
    float w0 = topk_w[2 * t], w1 = topk_w[2 * t + 1];
    f32x4 a = ((const f32x4*)(out2 + (size_t)s0 * HD))[c];
    f32x4 b = ((const f32x4*)(out2 + (size_t)s1 * HD))[c];
    f32x4 o;
#pragma unroll
    for (int j = 0; j < 4; ++j) o[j] = w0 * a[j] + w1 * b[j];
    ((f32x4*)(y + (size_t)t * HD))[c] = o;
}

extern "C" void kernel_launch(void* const* d_in, const int* in_sizes, int n_in,
                              void* d_out, int out_size, void* d_ws, size_t ws_size,
                              hipStream_t stream) {
    (void)in_sizes; (void)n_in; (void)out_size; (void)ws_size;
    const float* x  = (const float*)d_in[0];
    const float* wg = (const float*)d_in[1];
    const float* w1 = (const float*)d_in[2];
    const float* w3 = (const float*)d_in[3];
    const float* w2 = (const float*)d_in[4];
    float* y = (float*)d_out;

    char* ws = (char*)d_ws;
    int*   counts   = (int*)(ws + 0);       // 8 ints
    int*   counts2  = (int*)(ws + 32);      // 8 ints
    int*   offsets  = (int*)(ws + 64);      // 8 ints
    int*   topk_idx = (int*)(ws + 128);                        // 4096 ints
    float* topk_w   = (float*)(ws + 128 + (size_t)NSLOT * 4);  // 4096 floats
    int*   rows     = (int*)(ws + 128 + (size_t)NSLOT * 8);    // 4352 ints
    int*   slot_of  = (int*)(ws + 128 + (size_t)NSLOT * 8 + (size_t)NSLOT_ALLOC * 4);
    size_t off_xbf = 128 + (size_t)NSLOT * 12 + (size_t)NSLOT_ALLOC * 4;
    off_xbf = (off_xbf + 255) & ~(size_t)255;
    u16* xbf = (u16*)(ws + off_xbf);
    size_t off_h = off_xbf + (size_t)NTOK * HD * 2;
    u16* hbuf = (u16*)(ws + off_h);
    size_t off_w1 = off_h + (size_t)NSLOT_ALLOC * ID * 2;
    u16* w1bf = (u16*)(ws + off_w1);
    size_t off_w3 = off_w1 + (size_t)WN * 2;
    u16* w3bf = (u16*)(ws + off_w3);
    size_t off_w2 = off_w3 + (size_t)WN * 2;
    u16* w2bf = (u16*)(ws + off_w2);
    size_t off_o2 = off_w2 + (size_t)WN * 2;
    float* out2 = (float*)(ws + off_o2);    // single partial buffer

    init_kernel<<<1, 64, 0, stream>>>(counts);
    pre_kernel<<<PRE_BLOCKS, 256, 0, stream>>>(x, wg, topk_idx, topk_w, counts,
                                               xbf, w1, w1bf, w3, w3bf);
    scan_kernel<<<1, 256, 0, stream>>>(counts, offsets, rows);
    assign_kernel<<<NSLOT / 256, 256, 0, stream>>>(topk_idx, offsets, counts2, rows, slot_of);
    gemm1_kernel<<<G1_BLOCKS + CVT2_BLOCKS, 256, 0, stream>>>(xbf, w1bf, w3bf, counts, offsets, rows, hbuf, w2, w2bf);
    gemm2_kernel<<<NEXP * (NTOK / 128) * (HD / 128), 256, 0, stream>>>(hbuf, w2bf, counts, offsets, out2);
    combine_kernel<<<(NTOK * HD / 4) / 256, 256, 0, stream>>>(out2, slot_of, topk_w, y);
}

// Round 20
// 326.587 us; speedup vs baseline: 1.0133x; 1.0133x over previous
//
#include <hip/hip_runtime.h>
#include <hip/hip_bf16.h>
#include <stdint.h>

#define NEXP 8
#define HD 1024
#define ID 3584
#define NTOK 2048
#define NSLOT 4096          // NTOK * TOPK
#define SLOT_PAD 256
#define NSLOT_ALLOC (NSLOT + SLOT_PAD)
#define WN (NEXP * ID * HD)   // elements per weight tensor = 29,360,128

typedef unsigned short u16;
typedef __attribute__((ext_vector_type(8))) short s16x8;
typedef __attribute__((ext_vector_type(4))) short s16x4;
typedef __attribute__((ext_vector_type(4))) float f32x4;

__device__ __forceinline__ u16 f2bf(float f) {
    __hip_bfloat16 h = __float2bfloat16(f);   // RNE
    union { __hip_bfloat16 h; u16 u; } v; v.h = h; return v.u;
}

__device__ __forceinline__ s16x8 cvt8(f32x4 a, f32x4 b) {
    s16x8 o;
    o[0]=(short)f2bf(a[0]); o[1]=(short)f2bf(a[1]); o[2]=(short)f2bf(a[2]); o[3]=(short)f2bf(a[3]);
    o[4]=(short)f2bf(b[0]); o[5]=(short)f2bf(b[1]); o[6]=(short)f2bf(b[2]); o[7]=(short)f2bf(b[3]);
    return o;
}

__device__ __forceinline__ void glds16(const void* g, void* l) {
    __builtin_amdgcn_global_load_lds((const __attribute__((address_space(1))) unsigned*)g,
                                     (__attribute__((address_space(3))) unsigned*)l, 16, 0, 0);
}

// wave-coalesced fp32->bf16, NON-TEMPORAL both directions:
// fp32 reads are read-once (never reused) and bf16 writes are consumed a dispatch
// later -> skip cache allocation, keep L2/L3 for streams that need them.
__device__ __forceinline__ void cvt_blk(const float* __restrict__ src, u16* __restrict__ dst, int blk) {
    size_t base = (size_t)blk * 2048 + threadIdx.x;
    const f32x4* s = (const f32x4*)src;
    s16x4* d = (s16x4*)dst;
#pragma unroll
    for (int j = 0; j < 8; ++j) {
        f32x4 v = __builtin_nontemporal_load(&s[base + j * 256]);
        s16x4 o;
        o[0] = (short)f2bf(v[0]); o[1] = (short)f2bf(v[1]);
        o[2] = (short)f2bf(v[2]); o[3] = (short)f2bf(v[3]);
        __builtin_nontemporal_store(o, &d[base + j * 256]);
    }
}

// ---------------- K0: zero counters ----------------
__global__ void init_kernel(int* __restrict__ counts) {
    if (threadIdx.x < 16) counts[threadIdx.x] = 0;   // counts[8] + counts2[8]
}

// ---------------- K1: FAT preprocessing ----------------
// blocks [0,512): router, 4 tokens/block.
// blocks [512,4096): w1 cvt   (3584 blocks x 2048 f32x4 = WN exactly)
// blocks [4096,7680): w3 cvt
// blocks [7680,7936): x cvt   (256 blocks x 2048 f32x4 = NTOK*HD exactly)
#define RT_BLOCKS 512
#define WCV_BLOCKS 3584
#define XCV_BLOCKS 256
#define PRE_BLOCKS (RT_BLOCKS + 2 * WCV_BLOCKS + XCV_BLOCKS)   // 7936
__global__ __launch_bounds__(256)
void pre_kernel(const float* __restrict__ x, const float* __restrict__ wg,
                int* __restrict__ topk_idx, float* __restrict__ topk_w,
                int* __restrict__ counts,
                u16* __restrict__ xbf,
                const float* __restrict__ w1, u16* __restrict__ w1bf,
                const float* __restrict__ w3, u16* __restrict__ w3bf) {
    int bid = blockIdx.x;
    if (bid >= RT_BLOCKS) {
        if (bid < RT_BLOCKS + WCV_BLOCKS) {
            cvt_blk(w1, w1bf, bid - RT_BLOCKS);
        } else if (bid < RT_BLOCKS + 2 * WCV_BLOCKS) {
            cvt_blk(w3, w3bf, bid - RT_BLOCKS - WCV_BLOCKS);
        } else {
            cvt_blk(x, xbf, bid - RT_BLOCKS - 2 * WCV_BLOCKS);
        }
        return;
    }
    // ---- router: 4 waves/block, 1 token/wave, fp32 exact top-2 ----
    int t = bid * 4 + (threadIdx.x >> 6);
    int lane = threadIdx.x & 63;
    const float* xr = x + (size_t)t * HD;
    float acc[NEXP];
#pragma unroll
    for (int e = 0; e < NEXP; ++e) acc[e] = 0.f;
#pragma unroll
    for (int i = 0; i < HD / 256; ++i) {
        int h = i * 256 + lane * 4;
        f32x4 xv = *(const f32x4*)(xr + h);
#pragma unroll
        for (int e = 0; e < NEXP; ++e) {
            f32x4 wv = *(const f32x4*)(wg + e * HD + h);
            acc[e] += xv[0]*wv[0] + xv[1]*wv[1] + xv[2]*wv[2] + xv[3]*wv[3];
        }
    }
#pragma unroll
    for (int e = 0; e < NEXP; ++e) {
#pragma unroll
        for (int s = 32; s > 0; s >>= 1) acc[e] += __shfl_xor(acc[e], s, 64);
    }
    if (lane == 0) {
        int b0 = 0; float l0 = acc[0];
#pragma unroll
        for (int e = 1; e < NEXP; ++e) if (acc[e] > l0) { l0 = acc[e]; b0 = e; }
        int b1 = (b0 == 0) ? 1 : 0; float l1 = acc[b1];
#pragma unroll
        for (int e = 0; e < NEXP; ++e) {
            if (e == b0 || e == b1) continue;
            if (acc[e] > l1) { l1 = acc[e]; b1 = e; }
        }
        float w0 = 1.f / (1.f + expf(l1 - l0));   // renormalized top-2 softmax
        float w1v = 1.f - w0;
        topk_idx[2 * t] = b0; topk_idx[2 * t + 1] = b1;
        topk_w[2 * t] = w0;  topk_w[2 * t + 1] = w1v;
        atomicAdd(&counts[b0], 1);
        atomicAdd(&counts[b1], 1);
    }
}

// ---------------- K2: exclusive scan + pad rows ----------------
__global__ void scan_kernel(const int* __restrict__ counts, int* __restrict__ offsets,
                            int* __restrict__ rows) {
    if (threadIdx.x == 0) {
        int off = 0;
#pragma unroll
        for (int e = 0; e < NEXP; ++e) { offsets[e] = off; off += counts[e]; }
    }
    if (threadIdx.x < SLOT_PAD) rows[NSLOT + threadIdx.x] = 0;
}

// ---------------- K3: slot assignment ----------------
__global__ void assign_kernel(const int* __restrict__ topk_idx, const int* __restrict__ offsets,
                              int* __restrict__ counts2, int* __restrict__ rows,
                              int* __restrict__ slot_of) {
    int i = blockIdx.x * 256 + threadIdx.x;   // 0..4095
    int e = topk_idx[i];
    int pos = atomicAdd(&counts2[e], 1);
    int slot = offsets[e] + pos;
    rows[slot] = i >> 1;       // token id
    slot_of[i] = slot;
}

// ---------------- K5: FAT kernel: GEMM1 (g,u)+SwiGLU -> h  ||  w2 cvt ----------------
// R14/R15 structure (byte-identical): 2-barrier BK=64, 128x128 tile, 4 waves, 48 KB LDS,
// 8-granule XOR swizzle (verified conflict-free), T1 panel-XCD remap, fat w2-cvt.
#define G1_BLOCKS (NEXP * (NTOK / 128) * (ID / 128))   // 3584
#define CVT2_BLOCKS 1024
__global__ __launch_bounds__(256, 2)
void gemm1_kernel(const u16* __restrict__ xbf, const u16* __restrict__ w1bf,
                  const u16* __restrict__ w3bf, const int* __restrict__ counts,
                  const int* __restrict__ offsets, const int* __restrict__ rows,
                  u16* __restrict__ hbuf,
                  const float* __restrict__ w2, u16* __restrict__ w2bf) {
    __shared__ u16 As[128][64];    // 16 KB
    __shared__ u16 B1s[128][64];   // 16 KB
    __shared__ u16 B3s[128][64];   // 16 KB

    if (blockIdx.x >= G1_BLOCKS) {
        // w2 cvt side job: coalesced + nontemporal (1024 blocks, grid-stride)
        const int nblk = WN / 4 / 2048;   // 3584 logical blocks
        for (int blk = blockIdx.x - G1_BLOCKS; blk < nblk; blk += CVT2_BLOCKS)
            cvt_blk(w2, w2bf, blk);
        return;
    }

    int bid = blockIdx.x;
    int gq = bid >> 7;            // 0..27
    int rm = bid & 127;
    int mt = rm >> 3;             // 0..15
    int g  = gq * 8 + (rm & 7);   // 0..223
    int e  = g / 28;              // NT = ID/128 = 28
    int nt = g - e * 28;

    int n_e = counts[e];
    int m0 = mt * 128;
    if (m0 >= n_e) return;
    int off = offsets[e];
    int n0 = nt * 128;

    int tid = threadIdx.x;
    int lane = tid & 63;
    int wid = tid >> 6;           // 0..3

    int rsub = lane >> 3;                       // 0..7
    int chunk = ((lane & 7) ^ rsub) * 8;        // pre-swizzled source offset (elems)
    int srow = wid * 32 + rsub;

    const u16 *srcA[4], *srcB1[4], *srcB3[4];
#pragma unroll
    for (int j = 0; j < 4; ++j) {
        int rl = srow + 8 * j;
        int tok = rows[off + m0 + rl];
        srcA[j]  = xbf  + (size_t)tok * HD + chunk;
        srcB1[j] = w1bf + ((size_t)e * ID + n0 + rl) * HD + chunk;
        srcB3[j] = w3bf + ((size_t)e * ID + n0 + rl) * HD + chunk;
    }

    f32x4 accg[4][4] = {}, accu[4][4] = {};
    int wm = (wid >> 1) * 64, wn = (wid & 1) * 64;
    int lr = lane & 15;
    int kk = lane >> 4;
    int ks0 = ((kk)     ^ (lr & 7)) * 8;
    int ks1 = ((4 + kk) ^ (lr & 7)) * 8;

    for (int k0 = 0; k0 < HD; k0 += 64) {        // 16 steps
#pragma unroll
        for (int j = 0; j < 4; ++j) {
            glds16(srcA[j]  + k0, &As[wid * 32 + 8 * j][0]);
            glds16(srcB1[j] + k0, &B1s[wid * 32 + 8 * j][0]);
            glds16(srcB3[j] + k0, &B3s[wid * 32 + 8 * j][0]);
        }
        __syncthreads();
        s16x8 a[4], b1[4], b3[4];
#pragma unroll
        for (int f = 0; f < 4; ++f) {
            a[f]  = *(const s16x8*)&As[wm + f * 16 + lr][ks0];
            b1[f] = *(const s16x8*)&B1s[wn + f * 16 + lr][ks0];
            b3[f] = *(const s16x8*)&B3s[wn + f * 16 + lr][ks0];
        }
#pragma unroll
        for (int fm = 0; fm < 4; ++fm)
#pragma unroll
            for (int fn = 0; fn < 4; ++fn) {
                accg[fm][fn] = __builtin_amdgcn_mfma_f32_16x16x32_bf16(a[fm], b1[fn], accg[fm][fn], 0, 0, 0);
                accu[fm][fn] = __builtin_amdgcn_mfma_f32_16x16x32_bf16(a[fm], b3[fn], accu[fm][fn], 0, 0, 0);
            }
#pragma unroll
        for (int f = 0; f < 4; ++f) {
            a[f]  = *(const s16x8*)&As[wm + f * 16 + lr][ks1];
            b1[f] = *(const s16x8*)&B1s[wn + f * 16 + lr][ks1];
            b3[f] = *(const s16x8*)&B3s[wn + f * 16 + lr][ks1];
        }
#pragma unroll
        for (int fm = 0; fm < 4; ++fm)
#pragma unroll
            for (int fn = 0; fn < 4; ++fn) {
                accg[fm][fn] = __builtin_amdgcn_mfma_f32_16x16x32_bf16(a[fm], b1[fn], accg[fm][fn], 0, 0, 0);
                accu[fm][fn] = __builtin_amdgcn_mfma_f32_16x16x32_bf16(a[fm], b3[fn], accu[fm][fn], 0, 0, 0);
            }
        __syncthreads();
    }

    int lc = lane & 15;
    int lr4 = (lane >> 4) * 4;
#pragma unroll
    for (int fm = 0; fm < 4; ++fm) {
#pragma unroll
        for (int r = 0; r < 4; ++r) {
            int row = wm + fm * 16 + lr4 + r;
            if (m0 + row < n_e) {
                size_t base = (size_t)(off + m0 + row) * ID + n0 + wn;
#pragma unroll
                for (int fn = 0; fn < 4; ++fn) {
                    float g2 = accg[fm][fn][r];
                    float u = accu[fm][fn][r];
                    float hv = g2 * u / (1.f + expf(-g2));   // silu(g)*u
                    hbuf[base + fn * 16 + lc] = f2bf(hv);
                }
            }
        }
    }
}

// ---------------- K6: GEMM2 h @ w2bf^T -> per-slot fp32, KSPLIT=1, BK=64 ----------------
__global__ __launch_bounds__(256, 2)
void gemm2_kernel(const u16* __restrict__ hbuf, const u16* __restrict__ w2bf,
                  const int* __restrict__ counts, const int* __restrict__ offsets,
                  float* __restrict__ out2) {
    int bid = blockIdx.x;
    int e = bid & 7;
    int inner = bid >> 3;        // 0..127
    int mt = inner >> 3;         // 0..15
    int nt = inner & 7;          // 0..7

    int n_e = counts[e];
    int m0 = mt * 128;
    if (m0 >= n_e) return;
    int off = offsets[e];
    int n0 = nt * 128;

    __shared__ u16 As[128][64];   // 16 KB
    __shared__ u16 Bs[128][64];   // 16 KB

    int tid = threadIdx.x;
    int lane = tid & 63;
    int wid = tid >> 6;

    int rsub = lane >> 3;
    int chunk = ((lane & 7) ^ rsub) * 8;
    int srow = wid * 32 + rsub;

    const u16 *srcA[4], *srcB[4];
#pragma unroll
    for (int j = 0; j < 4; ++j) {
        int rl = srow + 8 * j;
        srcA[j] = hbuf + (size_t)(off + m0 + rl) * ID + chunk;
        srcB[j] = w2bf + ((size_t)e * HD + n0 + rl) * ID + chunk;
    }

    f32x4 acc[4][4] = {};
    int wm = (wid >> 1) * 64, wn = (wid & 1) * 64;
    int lr = lane & 15;
    int kk = lane >> 4;
    int ks0 = ((kk)     ^ (lr & 7)) * 8;
    int ks1 = ((4 + kk) ^ (lr & 7)) * 8;

    for (int k0 = 0; k0 < ID; k0 += 64) {        // 56 steps
#pragma unroll
        for (int j = 0; j < 4; ++j) {
            glds16(srcA[j] + k0, &As[wid * 32 + 8 * j][0]);
            glds16(srcB[j] + k0, &Bs[wid * 32 + 8 * j][0]);
        }
        __syncthreads();
        s16x8 a[4], b[4];
#pragma unroll
        for (int f = 0; f < 4; ++f) {
            a[f] = *(const s16x8*)&As[wm + f * 16 + lr][ks0];
            b[f] = *(const s16x8*)&Bs[wn + f * 16 + lr][ks0];
        }
#pragma unroll
        for (int fm = 0; fm < 4; ++fm)
#pragma unroll
            for (int fn = 0; fn < 4; ++fn)
                acc[fm][fn] = __builtin_amdgcn_mfma_f32_16x16x32_bf16(a[fm], b[fn], acc[fm][fn], 0, 0, 0);
#pragma unroll
        for (int f = 0; f < 4; ++f) {
            a[f] = *(const s16x8*)&As[wm + f * 16 + lr][ks1];
            b[f] = *(const s16x8*)&Bs[wn + f * 16 + lr][ks1];
        }
#pragma unroll
        for (int fm = 0; fm < 4; ++fm)
#pragma unroll
            for (int fn = 0; fn < 4; ++fn)
                acc[fm][fn] = __builtin_amdgcn_mfma_f32_16x16x32_bf16(a[fm], b[fn], acc[fm][fn], 0, 0, 0);
        __syncthreads();
    }

    int lc = lane & 15;
    int lr4 = (lane >> 4) * 4;
#pragma unroll
    for (int fm = 0; fm < 4; ++fm) {
#pragma unroll
        for (int r = 0; r < 4; ++r) {
            int row = wm + fm * 16 + lr4 + r;
            if (m0 + row < n_e) {
                float* dst = out2 + (size_t)(off + m0 + row) * HD + n0 + wn;
#pragma unroll
                for (int fn = 0; fn < 4; ++fn)
                    dst[fn * 16 + lc] = acc[fm][fn][r];
            }
        }
    }
}

// ---------------- K7: weighted combine (single partial) ----------------
__global__ void combine_kernel(const float* __restrict__ out2, const int* __restrict__ slot_of,
                               const float* __restrict__ topk_w, float* __restrict__ y) {
    int i = blockIdx.x * 256 + threadIdx.x;   // over NTOK*HD/4
    int t = i >> 8;           // HD/4 = 256 float4 per token
    int c = i & 255;
    int s0 = slot_of[2 * t], s1 = slot_of[2 * t + 1];
    float w0 = topk_w[2 * t], w1 = topk_w[2 * t + 1];
    f32x4 a = ((const f32x4*)(out2 + (size_t)s0 * HD))[c];
    f32x4 b = ((const f32x4*)(out2 + (size_t)s1 * HD))[c];
    f32x4 o;
#pragma unroll
    for (int j = 0; j < 4; ++j) o[j] = w0 * a[j] + w1 * b[j];
    ((f32x4*)(y + (size_t)t * HD))[c] = o;
}

extern "C" void kernel_launch(void* const* d_in, const int* in_sizes, int n_in,
                              void* d_out, int out_size, void* d_ws, size_t ws_size,
                              hipStream_t stream) {
    (void)in_sizes; (void)n_in; (void)out_size; (void)ws_size;
    const float* x  = (const float*)d_in[0];
    const float* wg = (const float*)d_in[1];
    const float* w1 = (const float*)d_in[2];
    const float* w3 = (const float*)d_in[3];
    const float* w2 = (const float*)d_in[4];
    float* y = (float*)d_out;

    char* ws = (char*)d_ws;
    int*   counts   = (int*)(ws + 0);       // 8 ints
    int*   counts2  = (int*)(ws + 32);      // 8 ints
    int*   offsets  = (int*)(ws + 64);      // 8 ints
    int*   topk_idx = (int*)(ws + 128);                        // 4096 ints
    float* topk_w   = (float*)(ws + 128 + (size_t)NSLOT * 4);  // 4096 floats
    int*   rows     = (int*)(ws + 128 + (size_t)NSLOT * 8);    // 4352 ints
    int*   slot_of  = (int*)(ws + 128 + (size_t)NSLOT * 8 + (size_t)NSLOT_ALLOC * 4);
    size_t off_xbf = 128 + (size_t)NSLOT * 12 + (size_t)NSLOT_ALLOC * 4;
    off_xbf = (off_xbf + 255) & ~(size_t)255;
    u16* xbf = (u16*)(ws + off_xbf);
    size_t off_h = off_xbf + (size_t)NTOK * HD * 2;
    u16* hbuf = (u16*)(ws + off_h);
    size_t off_w1 = off_h + (size_t)NSLOT_ALLOC * ID * 2;
    u16* w1bf = (u16*)(ws + off_w1);
    size_t off_w3 = off_w1 + (size_t)WN * 2;
    u16* w3bf = (u16*)(ws + off_w3);
    size_t off_w2 = off_w3 + (size_t)WN * 2;
    u16* w2bf = (u16*)(ws + off_w2);
    size_t off_o2 = off_w2 + (size_t)WN * 2;
    float* out2 = (float*)(ws + off_o2);    // single partial buffer

    init_kernel<<<1, 64, 0, stream>>>(counts);
    pre_kernel<<<PRE_BLOCKS, 256, 0, stream>>>(x, wg, topk_idx, topk_w, counts,
                                               xbf, w1, w1bf, w3, w3bf);
    scan_kernel<<<1, 256, 0, stream>>>(counts, offsets, rows);
    assign_kernel<<<NSLOT / 256, 256, 0, stream>>>(topk_idx, offsets, counts2, rows, slot_of);
    gemm1_kernel<<<G1_BLOCKS + CVT2_BLOCKS, 256, 0, stream>>>(xbf, w1bf, w3bf, counts, offsets, rows, hbuf, w2, w2bf);
    gemm2_kernel<<<NEXP * (NTOK / 128) * (HD / 128), 256, 0, stream>>>(hbuf, w2bf, counts, offsets, out2);
    combine_kernel<<<(NTOK * HD / 4) / 256, 256, 0, stream>>>(out2, slot_of, topk_w, y);
}

// Round 21
// 285.196 us; speedup vs baseline: 1.1604x; 1.1451x over previous
//
#include <hip/hip_runtime.h>
#include <hip/hip_bf16.h>
#include <stdint.h>

#define NEXP 8
#define HD 1024
#define ID 3584
#define NTOK 2048
#define NSLOT 4096          // NTOK * TOPK
#define SLOT_PAD 256
#define NSLOT_ALLOC (NSLOT + SLOT_PAD)
#define WN (NEXP * ID * HD)   // elements per weight tensor = 29,360,128

typedef unsigned short u16;
typedef __attribute__((ext_vector_type(8))) short s16x8;
typedef __attribute__((ext_vector_type(4))) short s16x4;
typedef __attribute__((ext_vector_type(4))) float f32x4;

__device__ __forceinline__ u16 f2bf(float f) {
    __hip_bfloat16 h = __float2bfloat16(f);   // RNE
    union { __hip_bfloat16 h; u16 u; } v; v.h = h; return v.u;
}

__device__ __forceinline__ s16x8 cvt8(f32x4 a, f32x4 b) {
    s16x8 o;
    o[0]=(short)f2bf(a[0]); o[1]=(short)f2bf(a[1]); o[2]=(short)f2bf(a[2]); o[3]=(short)f2bf(a[3]);
    o[4]=(short)f2bf(b[0]); o[5]=(short)f2bf(b[1]); o[6]=(short)f2bf(b[2]); o[7]=(short)f2bf(b[3]);
    return o;
}

__device__ __forceinline__ void glds16(const void* g, void* l) {
    __builtin_amdgcn_global_load_lds((const __attribute__((address_space(1))) unsigned*)g,
                                     (__attribute__((address_space(3))) unsigned*)l, 16, 0, 0);
}

// wave-coalesced fp32->bf16. NT on the fp32 LOADS only (read-once, never reused).
// bf16 STORES stay cache-allocating: 176 MB of bf16 weights fit L3 and are consumed
// by the next dispatch (R20 A/B: NT stores cost gemm1 +12 us re-fetching from HBM).
__device__ __forceinline__ void cvt_blk(const float* __restrict__ src, u16* __restrict__ dst, int blk) {
    size_t base = (size_t)blk * 2048 + threadIdx.x;
    const f32x4* s = (const f32x4*)src;
    s16x4* d = (s16x4*)dst;
#pragma unroll
    for (int j = 0; j < 8; ++j) {
        f32x4 v = __builtin_nontemporal_load(&s[base + j * 256]);
        s16x4 o;
        o[0] = (short)f2bf(v[0]); o[1] = (short)f2bf(v[1]);
        o[2] = (short)f2bf(v[2]); o[3] = (short)f2bf(v[3]);
        d[base + j * 256] = o;
    }
}

// ---------------- K0: zero counters ----------------
__global__ void init_kernel(int* __restrict__ counts) {
    if (threadIdx.x < 16) counts[threadIdx.x] = 0;   // counts[8] + counts2[8]
}

// ---------------- K1: FAT preprocessing ----------------
// blocks [0,512): router, 4 tokens/block.
// blocks [512,4096): w1 cvt   (3584 blocks x 2048 f32x4 = WN exactly)
// blocks [4096,7680): w3 cvt
// blocks [7680,7936): x cvt   (256 blocks x 2048 f32x4 = NTOK*HD exactly)
#define RT_BLOCKS 512
#define WCV_BLOCKS 3584
#define XCV_BLOCKS 256
#define PRE_BLOCKS (RT_BLOCKS + 2 * WCV_BLOCKS + XCV_BLOCKS)   // 7936
__global__ __launch_bounds__(256)
void pre_kernel(const float* __restrict__ x, const float* __restrict__ wg,
                int* __restrict__ topk_idx, float* __restrict__ topk_w,
                int* __restrict__ counts,
                u16* __restrict__ xbf,
                const float* __restrict__ w1, u16* __restrict__ w1bf,
                const float* __restrict__ w3, u16* __restrict__ w3bf) {
    int bid = blockIdx.x;
    if (bid >= RT_BLOCKS) {
        if (bid < RT_BLOCKS + WCV_BLOCKS) {
            cvt_blk(w1, w1bf, bid - RT_BLOCKS);
        } else if (bid < RT_BLOCKS + 2 * WCV_BLOCKS) {
            cvt_blk(w3, w3bf, bid - RT_BLOCKS - WCV_BLOCKS);
        } else {
            cvt_blk(x, xbf, bid - RT_BLOCKS - 2 * WCV_BLOCKS);
        }
        return;
    }
    // ---- router: 4 waves/block, 1 token/wave, fp32 exact top-2 ----
    int t = bid * 4 + (threadIdx.x >> 6);
    int lane = threadIdx.x & 63;
    const float* xr = x + (size_t)t * HD;
    float acc[NEXP];
#pragma unroll
    for (int e = 0; e < NEXP; ++e) acc[e] = 0.f;
#pragma unroll
    for (int i = 0; i < HD / 256; ++i) {
        int h = i * 256 + lane * 4;
        f32x4 xv = *(const f32x4*)(xr + h);
#pragma unroll
        for (int e = 0; e < NEXP; ++e) {
            f32x4 wv = *(const f32x4*)(wg + e * HD + h);
            acc[e] += xv[0]*wv[0] + xv[1]*wv[1] + xv[2]*wv[2] + xv[3]*wv[3];
        }
    }
#pragma unroll
    for (int e = 0; e < NEXP; ++e) {
#pragma unroll
        for (int s = 32; s > 0; s >>= 1) acc[e] += __shfl_xor(acc[e], s, 64);
    }
    if (lane == 0) {
        int b0 = 0; float l0 = acc[0];
#pragma unroll
        for (int e = 1; e < NEXP; ++e) if (acc[e] > l0) { l0 = acc[e]; b0 = e; }
        int b1 = (b0 == 0) ? 1 : 0; float l1 = acc[b1];
#pragma unroll
        for (int e = 0; e < NEXP; ++e) {
            if (e == b0 || e == b1) continue;
            if (acc[e] > l1) { l1 = acc[e]; b1 = e; }
        }
        float w0 = 1.f / (1.f + expf(l1 - l0));   // renormalized top-2 softmax
        float w1v = 1.f - w0;
        topk_idx[2 * t] = b0; topk_idx[2 * t + 1] = b1;
        topk_w[2 * t] = w0;  topk_w[2 * t + 1] = w1v;
        atomicAdd(&counts[b0], 1);
        atomicAdd(&counts[b1], 1);
    }
}

// ---------------- K2: exclusive scan + pad rows ----------------
__global__ void scan_kernel(const int* __restrict__ counts, int* __restrict__ offsets,
                            int* __restrict__ rows) {
    if (threadIdx.x == 0) {
        int off = 0;
#pragma unroll
        for (int e = 0; e < NEXP; ++e) { offsets[e] = off; off += counts[e]; }
    }
    if (threadIdx.x < SLOT_PAD) rows[NSLOT + threadIdx.x] = 0;
}

// ---------------- K3: slot assignment ----------------
__global__ void assign_kernel(const int* __restrict__ topk_idx, const int* __restrict__ offsets,
                              int* __restrict__ counts2, int* __restrict__ rows,
                              int* __restrict__ slot_of) {
    int i = blockIdx.x * 256 + threadIdx.x;   // 0..4095
    int e = topk_idx[i];
    int pos = atomicAdd(&counts2[e], 1);
    int slot = offsets[e] + pos;
    rows[slot] = i >> 1;       // token id
    slot_of[i] = slot;
}

// ---------------- K5: FAT kernel: GEMM1 (g,u)+SwiGLU -> h  ||  w2 cvt ----------------
// R14/R15 structure (byte-identical): 2-barrier BK=64, 128x128 tile, 4 waves, 48 KB LDS,
// 8-granule XOR swizzle (verified conflict-free), T1 panel-XCD remap, fat w2-cvt.
#define G1_BLOCKS (NEXP * (NTOK / 128) * (ID / 128))   // 3584
#define CVT2_BLOCKS 1024
__global__ __launch_bounds__(256, 2)
void gemm1_kernel(const u16* __restrict__ xbf, const u16* __restrict__ w1bf,
                  const u16* __restrict__ w3bf, const int* __restrict__ counts,
                  const int* __restrict__ offsets, const int* __restrict__ rows,
                  u16* __restrict__ hbuf,
                  const float* __restrict__ w2, u16* __restrict__ w2bf) {
    __shared__ u16 As[128][64];    // 16 KB
    __shared__ u16 B1s[128][64];   // 16 KB
    __shared__ u16 B3s[128][64];   // 16 KB

    if (blockIdx.x >= G1_BLOCKS) {
        // w2 cvt side job: coalesced, NT loads, cached stores (1024 blocks, grid-stride)
        const int nblk = WN / 4 / 2048;   // 3584 logical blocks
        for (int blk = blockIdx.x - G1_BLOCKS; blk < nblk; blk += CVT2_BLOCKS)
            cvt_blk(w2, w2bf, blk);
        return;
    }

    int bid = blockIdx.x;
    int gq = bid >> 7;            // 0..27
    int rm = bid & 127;
    int mt = rm >> 3;             // 0..15
    int g  = gq * 8 + (rm & 7);   // 0..223
    int e  = g / 28;              // NT = ID/128 = 28
    int nt = g - e * 28;

    int n_e = counts[e];
    int m0 = mt * 128;
    if (m0 >= n_e) return;
    int off = offsets[e];
    int n0 = nt * 128;

    int tid = threadIdx.x;
    int lane = tid & 63;
    int wid = tid >> 6;           // 0..3

    int rsub = lane >> 3;                       // 0..7
    int chunk = ((lane & 7) ^ rsub) * 8;        // pre-swizzled source offset (elems)
    int srow = wid * 32 + rsub;

    const u16 *srcA[4], *srcB1[4], *srcB3[4];
#pragma unroll
    for (int j = 0; j < 4; ++j) {
        int rl = srow + 8 * j;
        int tok = rows[off + m0 + rl];
        srcA[j]  = xbf  + (size_t)tok * HD + chunk;
        srcB1[j] = w1bf + ((size_t)e * ID + n0 + rl) * HD + chunk;
        srcB3[j] = w3bf + ((size_t)e * ID + n0 + rl) * HD + chunk;
    }

    f32x4 accg[4][4] = {}, accu[4][4] = {};
    int wm = (wid >> 1) * 64, wn = (wid & 1) * 64;
    int lr = lane & 15;
    int kk = lane >> 4;
    int ks0 = ((kk)     ^ (lr & 7)) * 8;
    int ks1 = ((4 + kk) ^ (lr & 7)) * 8;

    for (int k0 = 0; k0 < HD; k0 += 64) {        // 16 steps
#pragma unroll
        for (int j = 0; j < 4; ++j) {
            glds16(srcA[j]  + k0, &As[wid * 32 + 8 * j][0]);
            glds16(srcB1[j] + k0, &B1s[wid * 32 + 8 * j][0]);
            glds16(srcB3[j] + k0, &B3s[wid * 32 + 8 * j][0]);
        }
        __syncthreads();
        s16x8 a[4], b1[4], b3[4];
#pragma unroll
        for (int f = 0; f < 4; ++f) {
            a[f]  = *(const s16x8*)&As[wm + f * 16 + lr][ks0];
            b1[f] = *(const s16x8*)&B1s[wn + f * 16 + lr][ks0];
            b3[f] = *(const s16x8*)&B3s[wn + f * 16 + lr][ks0];
        }
#pragma unroll
        for (int fm = 0; fm < 4; ++fm)
#pragma unroll
            for (int fn = 0; fn < 4; ++fn) {
                accg[fm][fn] = __builtin_amdgcn_mfma_f32_16x16x32_bf16(a[fm], b1[fn], accg[fm][fn], 0, 0, 0);
                accu[fm][fn] = __builtin_amdgcn_mfma_f32_16x16x32_bf16(a[fm], b3[fn], accu[fm][fn], 0, 0, 0);
            }
#pragma unroll
        for (int f = 0; f < 4; ++f) {
            a[f]  = *(const s16x8*)&As[wm + f * 16 + lr][ks1];
            b1[f] = *(const s16x8*)&B1s[wn + f * 16 + lr][ks1];
            b3[f] = *(const s16x8*)&B3s[wn + f * 16 + lr][ks1];
        }
#pragma unroll
        for (int fm = 0; fm < 4; ++fm)
#pragma unroll
            for (int fn = 0; fn < 4; ++fn) {
                accg[fm][fn] = __builtin_amdgcn_mfma_f32_16x16x32_bf16(a[fm], b1[fn], accg[fm][fn], 0, 0, 0);
                accu[fm][fn] = __builtin_amdgcn_mfma_f32_16x16x32_bf16(a[fm], b3[fn], accu[fm][fn], 0, 0, 0);
            }
        __syncthreads();
    }

    int lc = lane & 15;
    int lr4 = (lane >> 4) * 4;
#pragma unroll
    for (int fm = 0; fm < 4; ++fm) {
#pragma unroll
        for (int r = 0; r < 4; ++r) {
            int row = wm + fm * 16 + lr4 + r;
            if (m0 + row < n_e) {
                size_t base = (size_t)(off + m0 + row) * ID + n0 + wn;
#pragma unroll
                for (int fn = 0; fn < 4; ++fn) {
                    float g2 = accg[fm][fn][r];
                    float u = accu[fm][fn][r];
                    float hv = g2 * u / (1.f + expf(-g2));   // silu(g)*u
                    hbuf[base + fn * 16 + lc] = f2bf(hv);
                }
            }
        }
    }
}

// ---------------- K6: GEMM2 h @ w2bf^T -> per-slot fp32, KSPLIT=1, BK=64 ----------------
__global__ __launch_bounds__(256, 2)
void gemm2_kernel(const u16* __restrict__ hbuf, const u16* __restrict__ w2bf,
                  const int* __restrict__ counts, const int* __restrict__ offsets,
                  float* __restrict__ out2) {
    int bid = blockIdx.x;
    int e = bid & 7;
    int inner = bid >> 3;        // 0..127
    int mt = inner >> 3;         // 0..15
    int nt = inner & 7;          // 0..7

    int n_e = counts[e];
    int m0 = mt * 128;
    if (m0 >= n_e) return;
    int off = offsets[e];
    int n0 = nt * 128;

    __shared__ u16 As[128][64];   // 16 KB
    __shared__ u16 Bs[128][64];   // 16 KB

    int tid = threadIdx.x;
    int lane = tid & 63;
    int wid = tid >> 6;

    int rsub = lane >> 3;
    int chunk = ((lane & 7) ^ rsub) * 8;
    int srow = wid * 32 + rsub;

    const u16 *srcA[4], *srcB[4];
#pragma unroll
    for (int j = 0; j < 4; ++j) {
        int rl = srow + 8 * j;
        srcA[j] = hbuf + (size_t)(off + m0 + rl) * ID + chunk;
        srcB[j] = w2bf + ((size_t)e * HD + n0 + rl) * ID + chunk;
    }

    f32x4 acc[4][4] = {};
    int wm = (wid >> 1) * 64, wn = (wid & 1) * 64;
    int lr = lane & 15;
    int kk = lane >> 4;
    int ks0 = ((kk)     ^ (lr & 7)) * 8;
    int ks1 = ((4 + kk) ^ (lr & 7)) * 8;

    for (int k0 = 0; k0 < ID; k0 += 64) {        // 56 steps
#pragma unroll
        for (int j = 0; j < 4; ++j) {
            glds16(srcA[j] + k0, &As[wid * 32 + 8 * j][0]);
            glds16(srcB[j] + k0, &Bs[wid * 32 + 8 * j][0]);
        }
        __syncthreads();
        s16x8 a[4], b[4];
#pragma unroll
        for (int f = 0; f < 4; ++f) {
            a[f] = *(const s16x8*)&As[wm + f * 16 + lr][ks0];
            b[f] = *(const s16x8*)&Bs[wn + f * 16 + lr][ks0];
        }
#pragma unroll
        for (int fm = 0; fm < 4; ++fm)
#pragma unroll
            for (int fn = 0; fn < 4; ++fn)
                acc[fm][fn] = __builtin_amdgcn_mfma_f32_16x16x32_bf16(a[fm], b[fn], acc[fm][fn], 0, 0, 0);
#pragma unroll
        for (int f = 0; f < 4; ++f) {
            a[f] = *(const s16x8*)&As[wm + f * 16 + lr][ks1];
            b[f] = *(const s16x8*)&Bs[wn + f * 16 + lr][ks1];
        }
#pragma unroll
        for (int fm = 0; fm < 4; ++fm)
#pragma unroll
            for (int fn = 0; fn < 4; ++fn)
                acc[fm][fn] = __builtin_amdgcn_mfma_f32_16x16x32_bf16(a[fm], b[fn], acc[fm][fn], 0, 0, 0);
        __syncthreads();
    }

    int lc = lane & 15;
    int lr4 = (lane >> 4) * 4;
#pragma unroll
    for (int fm = 0; fm < 4; ++fm) {
#pragma unroll
        for (int r = 0; r < 4; ++r) {
            int row = wm + fm * 16 + lr4 + r;
            if (m0 + row < n_e) {
                float* dst = out2 + (size_t)(off + m0 + row) * HD + n0 + wn;
#pragma unroll
                for (int fn = 0; fn < 4; ++fn)
                    dst[fn * 16 + lc] = acc[fm][fn][r];
            }
        }
    }
}

// ---------------- K7: weighted combine (single partial) ----------------
__global__ void combine_kernel(const float* __restrict__ out2, const int* __restrict__ slot_of,
                               const float* __restrict__ topk_w, float* __restrict__ y) {
    int i = blockIdx.x * 256 + threadIdx.x;   // over NTOK*HD/4
    int t = i >> 8;           // HD/4 = 256 float4 per token
    int c = i & 255;
    int s0 = slot_of[2 * t], s1 = slot_of[2 * t + 1];
    float w0 = topk_w[2 * t], w1 = topk_w[2 * t + 1];
    f32x4 a = ((const f32x4*)(out2 + (size_t)s0 * HD))[c];
    f32x4 b = ((const f32x4*)(out2 + (size_t)s1 * HD))[c];
    f32x4 o;
#pragma unroll
    for (int j = 0; j < 4; ++j) o[j] = w0 * a[j] + w1 * b[j];
    ((f32x4*)(y + (size_t)t * HD))[c] = o;
}

extern "C" void kernel_launch(void* const* d_in, const int* in_sizes, int n_in,
                              void* d_out, int out_size, void* d_ws, size_t ws_size,
                              hipStream_t stream) {
    (void)in_sizes; (void)n_in; (void)out_size; (void)ws_size;
    const float* x  = (const float*)d_in[0];
    const float* wg = (const float*)d_in[1];
    const float* w1 = (const float*)d_in[2];
    const float* w3 = (const float*)d_in[3];
    const float* w2 = (const float*)d_in[4];
    float* y = (float*)d_out;

    char* ws = (char*)d_ws;
    int*   counts   = (int*)(ws + 0);       // 8 ints
    int*   counts2  = (int*)(ws + 32);      // 8 ints
    int*   offsets  = (int*)(ws + 64);      // 8 ints
    int*   topk_idx = (int*)(ws + 128);                        // 4096 ints
    float* topk_w   = (float*)(ws + 128 + (size_t)NSLOT * 4);  // 4096 floats
    int*   rows     = (int*)(ws + 128 + (size_t)NSLOT * 8);    // 4352 ints
    int*   slot_of  = (int*)(ws + 128 + (size_t)NSLOT * 8 + (size_t)NSLOT_ALLOC * 4);
    size_t off_xbf = 128 + (size_t)NSLOT * 12 + (size_t)NSLOT_ALLOC * 4;
    off_xbf = (off_xbf + 255) & ~(size_t)255;
    u16* xbf = (u16*)(ws + off_xbf);
    size_t off_h = off_xbf + (size_t)NTOK * HD * 2;
    u16* hbuf = (u16*)(ws + off_h);
    size_t off_w1 = off_h + (size_t)NSLOT_ALLOC * ID * 2;
    u16* w1bf = (u16*)(ws + off_w1);
    size_t off_w3 = off_w1 + (size_t)WN * 2;
    u16* w3bf = (u16*)(ws + off_w3);
    size_t off_w2 = off_w3 + (size_t)WN * 2;
    u16* w2bf = (u16*)(ws + off_w2);
    size_t off_o2 = off_w2 + (size_t)WN * 2;
    float* out2 = (float*)(ws + off_o2);    // single partial buffer

    init_kernel<<<1, 64, 0, stream>>>(counts);
    pre_kernel<<<PRE_BLOCKS, 256, 0, stream>>>(x, wg, topk_idx, topk_w, counts,
                                               xbf, w1, w1bf, w3, w3bf);
    scan_kernel<<<1, 256, 0, stream>>>(counts, offsets, rows);
    assign_kernel<<<NSLOT / 256, 256, 0, stream>>>(topk_idx, offsets, counts2, rows, slot_of);
    gemm1_kernel<<<G1_BLOCKS + CVT2_BLOCKS, 256, 0, stream>>>(xbf, w1bf, w3bf, counts, offsets, rows, hbuf, w2, w2bf);
    gemm2_kernel<<<NEXP * (NTOK / 128) * (HD / 128), 256, 0, stream>>>(hbuf, w2bf, counts, offsets, out2);
    combine_kernel<<<(NTOK * HD / 4) / 256, 256, 0, stream>>>(out2, slot_of, topk_w, y);
}